// Round 3
// baseline (140.828 us; speedup 1.0000x reference)
//
#include <hip/hip_runtime.h>

// SharedGroupLinearLayer R5b (resubmit — previous round was a container
// infra failure, kernel never ran).
// R4 post-mortem: top-5 profiled dispatches are all 41us poison fills ->
// sgll_kernel itself is <41us; kernel-attributable time ~46us vs 21us HBM
// floor (~3 TB/s). Root cause: grid=512 = exactly 2 blocks/CU resident
// (launch_bounds allows 3) with zero backfill -> 8 waves/CU at low load
// duty cycle -> outstanding bytes/CU far below Little's-law need.
// R5: 1024 blocks x TPW=4 (full 16-load burst/wave, no refill) -> 3
// resident blocks/CU + continuous backfill; parity-duplicated R-frags so
// att is valid on ALL lanes (deletes the __shfl + lgkmcnt from the per-tile
// critical path); nontemporal stores (out is write-once).
//
// out[n,o] = (X w1^T + b1) + att0 * (X (w0-w1)^T + (b0-b1)),
// att0 = sigmoid(l0-l1); emb folded into acc init: C0 = b + E·W^T.

#define NBLK 1024   // x 4 waves x 4 tiles x 16 tokens = 262144
#define TPW  4      // tiles per wave, all resident in regs (full burst)

typedef short bf16x8 __attribute__((ext_vector_type(8)));
typedef float f32x4  __attribute__((ext_vector_type(4)));

union B8 { bf16x8 v; unsigned u[4]; };

__device__ __forceinline__ unsigned pk2bf(float lo, float hi) {
    unsigned a = __float_as_uint(lo) + 0x8000u;
    unsigned b = __float_as_uint(hi) + 0x8000u;
    return __builtin_amdgcn_perm(b, a, 0x07060302u);
}

__device__ __forceinline__ void pack8(B8& d, float4 p, float4 q) {
    d.u[0] = pk2bf(p.x, p.y); d.u[1] = pk2bf(p.z, p.w);
    d.u[2] = pk2bf(q.x, q.y); d.u[3] = pk2bf(q.z, q.w);
}

__global__ __launch_bounds__(256, 3) void sgll_kernel(
    const float* __restrict__ x,    // (262144, 64)
    const float* __restrict__ emb,  // (16, 64)  row = token % 16
    const float* __restrict__ rw,   // (64, 2)
    const float* __restrict__ ws,   // (2, 64, 64) w_stack[t][o][d]
    const float* __restrict__ bs,   // (2, 64)
    float* __restrict__ out)        // (262144, 64)
{
    __shared__ bf16x8 sW1[8][64];   // [kt*4+ot][lane]  w1 A-frags
    __shared__ bf16x8 sWd[8][64];   // w0-w1 A-frags

    const int tid  = threadIdx.x;
    const int lane = tid & 63;
    const int wv   = tid >> 6;
    const int col  = lane & 15;
    const int q    = lane >> 4;

    // ---- setup: stage W frags (waves split the 8 (kt,ot) combos) ----
    #pragma unroll
    for (int c = wv; c < 8; c += 4) {
        const int kt = c >> 2, ot = c & 3;
        const float* p0 = ws + (ot * 16 + col) * 64 + kt * 32 + q * 8;  // w0
        const float* p1 = p0 + 4096;                                    // w1
        float4 a0 = *(const float4*)p0, a1 = *(const float4*)(p0 + 4);
        float4 c0 = *(const float4*)p1, c1 = *(const float4*)(p1 + 4);
        B8 f1, fd;
        pack8(f1, c0, c1);
        fd.u[0] = pk2bf(a0.x - c0.x, a0.y - c0.y);
        fd.u[1] = pk2bf(a0.z - c0.z, a0.w - c0.w);
        fd.u[2] = pk2bf(a1.x - c1.x, a1.y - c1.y);
        fd.u[3] = pk2bf(a1.z - c1.z, a1.w - c1.w);
        sW1[c][lane] = f1.v;
        sWd[c][lane] = fd.v;
    }

    // ---- R frags (regs), duplicated across row parity:
    // A[m][k] = rw[k][m&1] -> C rows 4q+0 / 4q+1 = (l0, l1) on EVERY lane,
    // so att needs no cross-lane broadcast.
    B8 R0, R1;
    {
        const int c01 = col & 1;
        float v[8];
        #pragma unroll
        for (int j = 0; j < 8; ++j)
            v[j] = rw[(q * 8 + j) * 2 + c01];
        pack8(R0, make_float4(v[0], v[1], v[2], v[3]), make_float4(v[4], v[5], v[6], v[7]));
        #pragma unroll
        for (int j = 0; j < 8; ++j)
            v[j] = rw[(32 + q * 8 + j) * 2 + c01];
        pack8(R1, make_float4(v[0], v[1], v[2], v[3]), make_float4(v[4], v[5], v[6], v[7]));
    }

    // ---- E frags + bias combos (regs, per wave) ----
    B8 E0, E1;
    {
        const float* ep = emb + col * 64 + q * 8;
        pack8(E0, *(const float4*)ep, *(const float4*)(ep + 4));
        pack8(E1, *(const float4*)(ep + 32), *(const float4*)(ep + 36));
    }
    f32x4 bI1[4], bId[4];
    #pragma unroll
    for (int ot = 0; ot < 4; ++ot) {
        float4 b1 = *(const float4*)(bs + 64 + ot * 16 + q * 4);
        float4 b0 = *(const float4*)(bs + ot * 16 + q * 4);
        bI1[ot][0] = b1.x; bI1[ot][1] = b1.y; bI1[ot][2] = b1.z; bI1[ot][3] = b1.w;
        bId[ot][0] = b0.x - b1.x; bId[ot][1] = b0.y - b1.y;
        bId[ot][2] = b0.z - b1.z; bId[ot][3] = b0.w - b1.w;
    }

    __syncthreads();  // W frags ready

    // ---- full burst: all TPW tiles issued at once (16 dwordx4 in flight) ----
    const long base = (long)(blockIdx.x * 4 + wv) * (TPW * 16);   // first token
    float4 buf[TPW][4];
    #pragma unroll
    for (int t = 0; t < TPW; ++t) {
        const float* p = x + (base + (long)t * 16 + col) * 64 + q * 8;
        buf[t][0] = *(const float4*)p;        buf[t][1] = *(const float4*)(p + 4);
        buf[t][2] = *(const float4*)(p + 32); buf[t][3] = *(const float4*)(p + 36);
    }
    __builtin_amdgcn_sched_barrier(0);   // pin the burst before compute

    // ---- acc init via MFMA (overlaps burst load latency) ----
    f32x4 I1[4], Id[4], Il;
    #pragma unroll
    for (int ot = 0; ot < 4; ++ot) {
        f32x4 a1 = bI1[ot], ad = bId[ot];
        a1 = __builtin_amdgcn_mfma_f32_16x16x32_bf16(sW1[ot][lane],     E0.v, a1, 0, 0, 0);
        a1 = __builtin_amdgcn_mfma_f32_16x16x32_bf16(sW1[4 + ot][lane], E1.v, a1, 0, 0, 0);
        ad = __builtin_amdgcn_mfma_f32_16x16x32_bf16(sWd[ot][lane],     E0.v, ad, 0, 0, 0);
        ad = __builtin_amdgcn_mfma_f32_16x16x32_bf16(sWd[4 + ot][lane], E1.v, ad, 0, 0, 0);
        I1[ot] = a1;
        Id[ot] = ad;
    }
    {
        f32x4 z = {0.f, 0.f, 0.f, 0.f};
        z = __builtin_amdgcn_mfma_f32_16x16x32_bf16(R0.v, E0.v, z, 0, 0, 0);
        z = __builtin_amdgcn_mfma_f32_16x16x32_bf16(R1.v, E1.v, z, 0, 0, 0);
        Il = z;
    }

    // ---- consume the TPW tiles ----
    #pragma unroll
    for (int i = 0; i < TPW; ++i) {
        B8 X0, X1;
        pack8(X0, buf[i][0], buf[i][1]);
        pack8(X1, buf[i][2], buf[i][3]);

        f32x4 lac = Il;
        lac = __builtin_amdgcn_mfma_f32_16x16x32_bf16(R0.v, X0.v, lac, 0, 0, 0);
        lac = __builtin_amdgcn_mfma_f32_16x16x32_bf16(R1.v, X1.v, lac, 0, 0, 0);
        // rows 4q+0 / 4q+1 hold (l0, l1) on every lane -> no shuffle
        const float att = 1.0f / (1.0f + __expf(lac[1] - lac[0]));

        const long rowoff = (base + (long)i * 16 + col) * 64;
        #pragma unroll
        for (int ot = 0; ot < 4; ++ot) {
            f32x4 y = I1[ot];
            y = __builtin_amdgcn_mfma_f32_16x16x32_bf16(sW1[ot][lane],     X0.v, y, 0, 0, 0);
            y = __builtin_amdgcn_mfma_f32_16x16x32_bf16(sW1[4 + ot][lane], X1.v, y, 0, 0, 0);
            f32x4 d = Id[ot];
            d = __builtin_amdgcn_mfma_f32_16x16x32_bf16(sWd[ot][lane],     X0.v, d, 0, 0, 0);
            d = __builtin_amdgcn_mfma_f32_16x16x32_bf16(sWd[4 + ot][lane], X1.v, d, 0, 0, 0);
            f32x4 o;
            o[0] = fmaf(att, d[0], y[0]);
            o[1] = fmaf(att, d[1], y[1]);
            o[2] = fmaf(att, d[2], y[2]);
            o[3] = fmaf(att, d[3], y[3]);
            __builtin_nontemporal_store(o, (f32x4*)(out + rowoff + ot * 16 + q * 4));
        }
    }
}

extern "C" void kernel_launch(void* const* d_in, const int* in_sizes, int n_in,
                              void* d_out, int out_size, void* d_ws, size_t ws_size,
                              hipStream_t stream) {
    const float* x   = (const float*)d_in[0];
    const float* emb = (const float*)d_in[1];
    const float* rw  = (const float*)d_in[2];
    const float* wsk = (const float*)d_in[3];
    const float* bs  = (const float*)d_in[4];
    float* out = (float*)d_out;
    sgll_kernel<<<NBLK, 256, 0, stream>>>(x, emb, rw, wsk, bs, out);
}

// Round 4
// 137.499 us; speedup vs baseline: 1.0242x; 1.0242x over previous
//
#include <hip/hip_runtime.h>

// SharedGroupLinearLayer R6.
// R5b post-mortem (first real sgll counters): 51us, 2.7 TB/s, occ 21%.
//  (1) WRITE_SIZE 95MB vs 67MB ideal: NT stores bypassed L2 so the two
//      64B half-line store instrs per 128B out-line never merged (+41%
//      write traffic) and NT completion-at-HBM clogged the vmcnt queue,
//      throttling load issue.  -> plain stores, let L2 merge.
//  (2) 1024 blocks over 768 resident slots = two generations (12 then
//      4 waves/CU) -> avg occ 21%.  -> 768 blocks (exactly 3/CU, one
//      generation), each wave grid-strides 5-6 tiles (16384/3072) with a
//      rotating depth-4 register pipeline, statically unrolled (named
//      buffers, no runtime-indexed arrays).
// hbm_bytes ~137MB is already minimal -> pure BW-utilization problem.
//
// out[n,o] = (X w1^T + b1) + att0 * (X (w0-w1)^T + (b0-b1)),
// att0 = sigmoid(l0-l1); emb folded into acc init: C0 = b + E·W^T.

#define NBLK   768                 // 3 blocks/CU exactly, all co-resident
#define WAVES  (NBLK * 4)          // 3072
#define NTILES 16384               // 262144 tokens / 16 per tile

typedef short bf16x8 __attribute__((ext_vector_type(8)));
typedef float f32x4  __attribute__((ext_vector_type(4)));

union B8 { bf16x8 v; unsigned u[4]; };

__device__ __forceinline__ unsigned pk2bf(float lo, float hi) {
    unsigned a = __float_as_uint(lo) + 0x8000u;
    unsigned b = __float_as_uint(hi) + 0x8000u;
    return __builtin_amdgcn_perm(b, a, 0x07060302u);
}

__device__ __forceinline__ void pack8(B8& d, float4 p, float4 q) {
    d.u[0] = pk2bf(p.x, p.y); d.u[1] = pk2bf(p.z, p.w);
    d.u[2] = pk2bf(q.x, q.y); d.u[3] = pk2bf(q.z, q.w);
}

__global__ __launch_bounds__(256, 3) void sgll_kernel(
    const float* __restrict__ x,    // (262144, 64)
    const float* __restrict__ emb,  // (16, 64)  row = token % 16
    const float* __restrict__ rw,   // (64, 2)
    const float* __restrict__ ws,   // (2, 64, 64) w_stack[t][o][d]
    const float* __restrict__ bs,   // (2, 64)
    float* __restrict__ out)        // (262144, 64)
{
    __shared__ bf16x8 sW1[8][64];   // [kt*4+ot][lane]  w1 A-frags
    __shared__ bf16x8 sWd[8][64];   // w0-w1 A-frags

    const int tid  = threadIdx.x;
    const int lane = tid & 63;
    const int wv   = tid >> 6;
    const int col  = lane & 15;
    const int q    = lane >> 4;

    // ---- setup: stage W frags (waves split the 8 (kt,ot) combos) ----
    #pragma unroll
    for (int c = wv; c < 8; c += 4) {
        const int kt = c >> 2, ot = c & 3;
        const float* p0 = ws + (ot * 16 + col) * 64 + kt * 32 + q * 8;  // w0
        const float* p1 = p0 + 4096;                                    // w1
        float4 a0 = *(const float4*)p0, a1 = *(const float4*)(p0 + 4);
        float4 c0 = *(const float4*)p1, c1 = *(const float4*)(p1 + 4);
        B8 f1, fd;
        pack8(f1, c0, c1);
        fd.u[0] = pk2bf(a0.x - c0.x, a0.y - c0.y);
        fd.u[1] = pk2bf(a0.z - c0.z, a0.w - c0.w);
        fd.u[2] = pk2bf(a1.x - c1.x, a1.y - c1.y);
        fd.u[3] = pk2bf(a1.z - c1.z, a1.w - c1.w);
        sW1[c][lane] = f1.v;
        sWd[c][lane] = fd.v;
    }

    // ---- R frags (regs), duplicated across row parity:
    // A[m][k] = rw[k][m&1] -> C rows 4q+0 / 4q+1 = (l0, l1) on EVERY lane.
    B8 R0, R1;
    {
        const int c01 = col & 1;
        float v[8];
        #pragma unroll
        for (int j = 0; j < 8; ++j)
            v[j] = rw[(q * 8 + j) * 2 + c01];
        pack8(R0, make_float4(v[0], v[1], v[2], v[3]), make_float4(v[4], v[5], v[6], v[7]));
        #pragma unroll
        for (int j = 0; j < 8; ++j)
            v[j] = rw[(32 + q * 8 + j) * 2 + c01];
        pack8(R1, make_float4(v[0], v[1], v[2], v[3]), make_float4(v[4], v[5], v[6], v[7]));
    }

    // ---- E frags + bias combos (regs, per wave) ----
    B8 E0, E1;
    {
        const float* ep = emb + col * 64 + q * 8;
        pack8(E0, *(const float4*)ep, *(const float4*)(ep + 4));
        pack8(E1, *(const float4*)(ep + 32), *(const float4*)(ep + 36));
    }
    f32x4 bI1[4], bId[4];
    #pragma unroll
    for (int ot = 0; ot < 4; ++ot) {
        float4 b1 = *(const float4*)(bs + 64 + ot * 16 + q * 4);
        float4 b0 = *(const float4*)(bs + ot * 16 + q * 4);
        bI1[ot][0] = b1.x; bI1[ot][1] = b1.y; bI1[ot][2] = b1.z; bI1[ot][3] = b1.w;
        bId[ot][0] = b0.x - b1.x; bId[ot][1] = b0.y - b1.y;
        bId[ot][2] = b0.z - b1.z; bId[ot][3] = b0.w - b1.w;
    }

    __syncthreads();  // W frags ready

    const int w = blockIdx.x * 4 + wv;   // wave id, 0..3071

    auto loadt = [&](float4 (&B)[4], int T) {
        const float* p = x + ((long)T * 16 + col) * 64 + q * 8;
        B[0] = *(const float4*)p;        B[1] = *(const float4*)(p + 4);
        B[2] = *(const float4*)(p + 32); B[3] = *(const float4*)(p + 36);
    };

    // ---- prologue: fill pipeline with tiles w + {0,1,2,3}*WAVES ----
    float4 bA[4], bB[4], bC[4], bD[4];
    loadt(bA, w);
    loadt(bB, w + WAVES);
    loadt(bC, w + 2 * WAVES);
    loadt(bD, w + 3 * WAVES);
    __builtin_amdgcn_sched_barrier(0);   // pin the burst before compute

    // ---- acc init via MFMA (overlaps prologue load latency) ----
    f32x4 I1[4], Id[4], Il;
    #pragma unroll
    for (int ot = 0; ot < 4; ++ot) {
        f32x4 a1 = bI1[ot], ad = bId[ot];
        a1 = __builtin_amdgcn_mfma_f32_16x16x32_bf16(sW1[ot][lane],     E0.v, a1, 0, 0, 0);
        a1 = __builtin_amdgcn_mfma_f32_16x16x32_bf16(sW1[4 + ot][lane], E1.v, a1, 0, 0, 0);
        ad = __builtin_amdgcn_mfma_f32_16x16x32_bf16(sWd[ot][lane],     E0.v, ad, 0, 0, 0);
        ad = __builtin_amdgcn_mfma_f32_16x16x32_bf16(sWd[4 + ot][lane], E1.v, ad, 0, 0, 0);
        I1[ot] = a1;
        Id[ot] = ad;
    }
    {
        f32x4 z = {0.f, 0.f, 0.f, 0.f};
        z = __builtin_amdgcn_mfma_f32_16x16x32_bf16(R0.v, E0.v, z, 0, 0, 0);
        z = __builtin_amdgcn_mfma_f32_16x16x32_bf16(R1.v, E1.v, z, 0, 0, 0);
        Il = z;
    }

    auto step = [&](float4 (&B)[4], int TI, bool refill, int RT) {
        B8 X0, X1;
        pack8(X0, B[0], B[1]);
        pack8(X1, B[2], B[3]);
        if (refill) loadt(B, RT);   // wave-uniform branch; keeps queue full

        f32x4 lac = Il;
        lac = __builtin_amdgcn_mfma_f32_16x16x32_bf16(R0.v, X0.v, lac, 0, 0, 0);
        lac = __builtin_amdgcn_mfma_f32_16x16x32_bf16(R1.v, X1.v, lac, 0, 0, 0);
        // rows 4q+0 / 4q+1 hold (l0, l1) on every lane -> no shuffle
        const float att = 1.0f / (1.0f + __expf(lac[1] - lac[0]));

        const long rowoff = ((long)TI * 16 + col) * 64;
        #pragma unroll
        for (int ot = 0; ot < 4; ++ot) {
            f32x4 y = I1[ot];
            y = __builtin_amdgcn_mfma_f32_16x16x32_bf16(sW1[ot][lane],     X0.v, y, 0, 0, 0);
            y = __builtin_amdgcn_mfma_f32_16x16x32_bf16(sW1[4 + ot][lane], X1.v, y, 0, 0, 0);
            f32x4 d = Id[ot];
            d = __builtin_amdgcn_mfma_f32_16x16x32_bf16(sWd[ot][lane],     X0.v, d, 0, 0, 0);
            d = __builtin_amdgcn_mfma_f32_16x16x32_bf16(sWd[4 + ot][lane], X1.v, d, 0, 0, 0);
            float4 o;
            o.x = fmaf(att, d[0], y[0]);
            o.y = fmaf(att, d[1], y[1]);
            o.z = fmaf(att, d[2], y[2]);
            o.w = fmaf(att, d[3], y[3]);
            *(float4*)(out + rowoff + ot * 16 + q * 4) = o;   // plain store: L2 merges halves
        }
    };

    // tiles per wave: 5 for all, +1 for waves with w < NTILES - 5*WAVES (=1024)
    const bool six = (w < NTILES - 5 * WAVES);

    step(bA, w,             true, w + 4 * WAVES);   // refill always valid (max 15359)
    step(bB, w +     WAVES, six,  w + 5 * WAVES);   // 6th tile only for w<1024
    step(bC, w + 2 * WAVES, false, 0);
    step(bD, w + 3 * WAVES, false, 0);
    step(bA, w + 4 * WAVES, false, 0);
    if (six)
        step(bB, w + 5 * WAVES, false, 0);
}

extern "C" void kernel_launch(void* const* d_in, const int* in_sizes, int n_in,
                              void* d_out, int out_size, void* d_ws, size_t ws_size,
                              hipStream_t stream) {
    const float* x   = (const float*)d_in[0];
    const float* emb = (const float*)d_in[1];
    const float* rw  = (const float*)d_in[2];
    const float* wsk = (const float*)d_in[3];
    const float* bs  = (const float*)d_in[4];
    float* out = (float*)d_out;
    sgll_kernel<<<NBLK, 256, 0, stream>>>(x, emb, rw, wsk, bs, out);
}